// Round 3
// baseline (167.237 us; speedup 1.0000x reference)
//
#include <hip/hip_runtime.h>
#include <math.h>

#define NB 64
#define NL 512
#define ND 768

static constexpr float kCosEps = 1e-8f;
static constexpr double kBnEps = 1e-5;

// ---- workspace layout (bytes) ---- (identical to round 2)
static constexpr size_t OFF_ACC = 0;                         // 2 doubles (sum, sumsq)
static constexpr size_t OFF_CSN = 256;                       // [8][NB][ND] f32 partial colsums of news
static constexpr size_t SZ_PART = (size_t)8 * NB * ND * 4;
static constexpr size_t OFF_CSP = OFF_CSN + SZ_PART;         // [8][NB][ND] f32 partial colsums of post
static constexpr size_t OFF_COS = OFF_CSP + SZ_PART;         // [NB][NL] f32 cosine
static constexpr size_t SZ_BL   = (size_t)NB * NL * 4;
static constexpr size_t OFF_HI  = OFF_COS + SZ_BL;           // interior conv rows
static constexpr size_t OFF_HT  = OFF_HI + SZ_BL;            // top row
static constexpr size_t OFF_HB  = OFF_HT + SZ_BL;            // bottom row
static constexpr size_t OFF_ABC = OFF_HB + SZ_BL;            // [NB][3] f32 (a, ct, cb)

__device__ __forceinline__ float dot4(float4 a, float4 b) {
    return a.x * b.x + a.y * b.y + a.z * b.z + a.w * b.w;
}

// ---------------------------------------------------------------------------
// k1 v3: per-(b,l) cosine + fused per-(b,d) column sums.
// grid = NB*8 (batch x 64-row tile), block = 512 thr = 8 waves, 8 rows/wave.
// NO cross-lane shuffles in the hot loop (round-2 was latency-bound on the
// 6-stage ds_swizzle chain + 64-VGPR load serialization). Per-row partials
// (nn,pp,npd) stay in registers for all 8 rows; one padded-LDS transpose
// reduce per block. launch_bounds(512,4) -> 128 VGPR so 12 float4 loads
// (2 rows) are in flight per step.
// ---------------------------------------------------------------------------
__global__ __launch_bounds__(512, 4) void k1_cos_colsum(
    const float* __restrict__ news, const float* __restrict__ post,
    float* __restrict__ cosv, float* __restrict__ csn_part,
    float* __restrict__ csp_part)
{
    __shared__ float buf[64 * 193];     // 49.4 KB: [lane][192 rowvar + pad]; reused for colsum [8][768]
    __shared__ float lds_s[192];        // reduced (nn,pp,npd) per row
    const int b    = blockIdx.x >> 3;
    const int tile = blockIdx.x & 7;
    const int tid  = threadIdx.x;
    const int wave = tid >> 6;          // 0..7
    const int lane = tid & 63;

    float an[12], ap[12];
    float nn[8], pp[8], npd[8];
#pragma unroll
    for (int k = 0; k < 12; ++k) { an[k] = 0.f; ap[k] = 0.f; }

#pragma unroll
    for (int rp = 0; rp < 4; ++rp) {
        const int ra = 2 * rp, rb = 2 * rp + 1;
        const int la = tile * 64 + ra * 8 + wave;
        const int lb = tile * 64 + rb * 8 + wave;
        const float4* nra = (const float4*)(news + ((size_t)b * NL + la) * ND);
        const float4* pra = (const float4*)(post + ((size_t)b * NL + la) * ND);
        const float4* nrb = (const float4*)(news + ((size_t)b * NL + lb) * ND);
        const float4* prb = (const float4*)(post + ((size_t)b * NL + lb) * ND);
        // issue all 12 loads before any use
        const float4 A0 = nra[lane], A1 = nra[lane + 64], A2 = nra[lane + 128];
        const float4 B0 = pra[lane], B1 = pra[lane + 64], B2 = pra[lane + 128];
        const float4 C0 = nrb[lane], C1 = nrb[lane + 64], C2 = nrb[lane + 128];
        const float4 D0 = prb[lane], D1 = prb[lane + 64], D2 = prb[lane + 128];

        nn[ra]  = dot4(A0, A0) + dot4(A1, A1) + dot4(A2, A2);
        pp[ra]  = dot4(B0, B0) + dot4(B1, B1) + dot4(B2, B2);
        npd[ra] = dot4(A0, B0) + dot4(A1, B1) + dot4(A2, B2);
        nn[rb]  = dot4(C0, C0) + dot4(C1, C1) + dot4(C2, C2);
        pp[rb]  = dot4(D0, D0) + dot4(D1, D1) + dot4(D2, D2);
        npd[rb] = dot4(C0, D0) + dot4(C1, D1) + dot4(C2, D2);

        an[0] += A0.x + C0.x; an[1]  += A0.y + C0.y;
        an[2] += A0.z + C0.z; an[3]  += A0.w + C0.w;
        an[4] += A1.x + C1.x; an[5]  += A1.y + C1.y;
        an[6] += A1.z + C1.z; an[7]  += A1.w + C1.w;
        an[8] += A2.x + C2.x; an[9]  += A2.y + C2.y;
        an[10] += A2.z + C2.z; an[11] += A2.w + C2.w;
        ap[0] += B0.x + D0.x; ap[1]  += B0.y + D0.y;
        ap[2] += B0.z + D0.z; ap[3]  += B0.w + D0.w;
        ap[4] += B1.x + D1.x; ap[5]  += B1.y + D1.y;
        ap[6] += B1.z + D1.z; ap[7]  += B1.w + D1.w;
        ap[8] += B2.x + D2.x; ap[9]  += B2.y + D2.y;
        ap[10] += B2.z + D2.z; ap[11] += B2.w + D2.w;
    }

    // ---- row-reduce via padded LDS transpose (no shuffles) ----
    // col = wave*24 + r*3 + v  (v: 0=nn,1=pp,2=npd), r=0..7
#pragma unroll
    for (int r = 0; r < 8; ++r) {
        const int c = wave * 24 + r * 3;
        buf[lane * 193 + c + 0] = nn[r];
        buf[lane * 193 + c + 1] = pp[r];
        buf[lane * 193 + c + 2] = npd[r];
    }
    __syncthreads();
    if (tid < 192) {
        float s = 0.f;
#pragma unroll
        for (int l = 0; l < 64; ++l) s += buf[l * 193 + tid];
        lds_s[tid] = s;
    }
    __syncthreads();

    // cos for the 64 rows of this block; triplet j: wave=j>>3, r=j&7
    if (tid < 64) {
        const int j = tid;
        const float snn = lds_s[3 * j + 0];
        const float spp = lds_s[3 * j + 1];
        const float snp = lds_s[3 * j + 2];
        const int row = (j & 7) * 8 + (j >> 3);
        const float dn = fmaxf(sqrtf(snn), kCosEps) * fmaxf(sqrtf(spp), kCosEps);
        cosv[b * NL + tile * 64 + row] = snp / dn;
    }

    // ---- colsum reduce, phase A (news); buf reused as [8][768] ----
    {
        float4* wrow = (float4*)&buf[wave * ND];
        wrow[lane]       = make_float4(an[0], an[1], an[2], an[3]);
        wrow[lane + 64]  = make_float4(an[4], an[5], an[6], an[7]);
        wrow[lane + 128] = make_float4(an[8], an[9], an[10], an[11]);
    }
    __syncthreads();
    for (int i = tid; i < ND; i += 512) {
        float s = 0.f;
#pragma unroll
        for (int w = 0; w < 8; ++w) s += buf[w * ND + i];
        csn_part[((size_t)tile * NB + b) * ND + i] = s;
    }
    __syncthreads();
    // ---- colsum reduce, phase B (post) ----
    {
        float4* wrow = (float4*)&buf[wave * ND];
        wrow[lane]       = make_float4(ap[0], ap[1], ap[2], ap[3]);
        wrow[lane + 64]  = make_float4(ap[4], ap[5], ap[6], ap[7]);
        wrow[lane + 128] = make_float4(ap[8], ap[9], ap[10], ap[11]);
    }
    __syncthreads();
    for (int i = tid; i < ND; i += 512) {
        float s = 0.f;
#pragma unroll
        for (int w = 0; w < 8; ++w) s += buf[w * ND + i];
        csp_part[((size_t)tile * NB + b) * ND + i] = s;
    }
}

// ---------------------------------------------------------------------------
// k2: 3-tap horizontal conv of cos row (3 vertical-weight variants) +
// fp64 global sum / sum-of-squares with multiplicities (1, L-2, 1).
// ---------------------------------------------------------------------------
__global__ __launch_bounds__(256) void k2_conv_stats(
    const float* __restrict__ cosv, const float* __restrict__ g,
    float* __restrict__ hi, float* __restrict__ ht, float* __restrict__ hb,
    double* __restrict__ acc)
{
    __shared__ float row[NL + 2];
    __shared__ double sred[8];
    const int b   = blockIdx.x;
    const int tid = threadIdx.x;
    if (tid == 0) { row[0] = 0.f; row[NL + 1] = 0.f; }
    for (int j = tid; j < NL; j += 256) row[j + 1] = cosv[b * NL + j];
    __syncthreads();

    const float ci0 = g[0] + g[3] + g[6], ci1 = g[1] + g[4] + g[7], ci2 = g[2] + g[5] + g[8];
    const float ct0 = g[3] + g[6],        ct1 = g[4] + g[7],        ct2 = g[5] + g[8];
    const float cb0 = g[0] + g[3],        cb1 = g[1] + g[4],        cb2 = g[2] + g[5];

    double s = 0.0, s2 = 0.0;
    for (int j = tid; j < NL; j += 256) {
        const float a = row[j], c = row[j + 1], d = row[j + 2];
        const float vi = ci0 * a + ci1 * c + ci2 * d;
        const float vt = ct0 * a + ct1 * c + ct2 * d;
        const float vb = cb0 * a + cb1 * c + cb2 * d;
        hi[b * NL + j] = vi; ht[b * NL + j] = vt; hb[b * NL + j] = vb;
        s  += (double)vi * (NL - 2) + (double)vt + (double)vb;
        s2 += (double)vi * vi * (NL - 2) + (double)vt * vt + (double)vb * vb;
    }
    const int lane = tid & 63, wave = tid >> 6;
#pragma unroll
    for (int m = 32; m >= 1; m >>= 1) { s += __shfl_xor(s, m); s2 += __shfl_xor(s2, m); }
    if (lane == 0) { sred[wave] = s; sred[4 + wave] = s2; }
    __syncthreads();
    if (tid == 0) {
        atomicAdd(&acc[0], sred[0] + sred[1] + sred[2] + sred[3]);
        atomicAdd(&acc[1], sred[4] + sred[5] + sred[6] + sred[7]);
    }
}

// ---------------------------------------------------------------------------
// k3: normalize (global BN), z = h_hat @ W^T + b for the 3 variants,
// collapsed softmax over l (multiplicities 1, L-2, 1), sum over n.
// ---------------------------------------------------------------------------
__global__ __launch_bounds__(256) void k3_linear_softmax(
    const float* __restrict__ hi, const float* __restrict__ ht,
    const float* __restrict__ hb, const float* __restrict__ W,
    const float* __restrict__ bias, const float* __restrict__ gamma,
    const float* __restrict__ beta, const double* __restrict__ acc,
    float* __restrict__ abc)
{
    __shared__ float shi[NL], sht[NL], shb[NL];
    __shared__ float sred[12];
    const int b   = blockIdx.x;
    const int tid = threadIdx.x;

    const double N   = (double)NB * NL * NL;
    const double mu  = acc[0] / N;
    const double var = acc[1] / N - mu * mu;
    const float  sc  = gamma[0] * (float)(1.0 / sqrt(var + kBnEps));
    const float  sh  = beta[0] - (float)mu * sc;

    for (int j = tid; j < NL; j += 256) {
        shi[j] = hi[b * NL + j] * sc + sh;
        sht[j] = ht[b * NL + j] * sc + sh;
        shb[j] = hb[b * NL + j] * sc + sh;
    }
    __syncthreads();

    const float4* s4i = (const float4*)shi;
    const float4* s4t = (const float4*)sht;
    const float4* s4b = (const float4*)shb;

    float sa = 0.f, st = 0.f, sb = 0.f;
    for (int n = tid; n < NL; n += 256) {
        const float4* wr = (const float4*)(W + (size_t)n * NL);
        float zi = 0.f, zt = 0.f, zb = 0.f;
        for (int m = 0; m < NL / 4; ++m) {
            const float4 w  = wr[m];
            const float4 vi = s4i[m], vt = s4t[m], vb = s4b[m];
            zi += w.x * vi.x + w.y * vi.y + w.z * vi.z + w.w * vi.w;
            zt += w.x * vt.x + w.y * vt.y + w.z * vt.z + w.w * vt.w;
            zb += w.x * vb.x + w.y * vb.y + w.z * vb.z + w.w * vb.w;
        }
        const float bv = bias[n];
        zi += bv; zt += bv; zb += bv;
        const float M  = fmaxf(zi, fmaxf(zt, zb));
        const float ei = expf(zi - M), et = expf(zt - M), eb = expf(zb - M);
        const float r  = 1.f / ((float)(NL - 2) * ei + et + eb);
        sa += ei * r; st += et * r; sb += eb * r;
    }
    const int lane = tid & 63, wave = tid >> 6;
#pragma unroll
    for (int m = 32; m >= 1; m >>= 1) {
        sa += __shfl_xor(sa, m); st += __shfl_xor(st, m); sb += __shfl_xor(sb, m);
    }
    if (lane == 0) { sred[wave * 3] = sa; sred[wave * 3 + 1] = st; sred[wave * 3 + 2] = sb; }
    __syncthreads();
    if (tid == 0) {
        abc[b * 3 + 0] = sred[0] + sred[3] + sred[6] + sred[9];
        abc[b * 3 + 1] = sred[1] + sred[4] + sred[7] + sred[10];
        abc[b * 3 + 2] = sred[2] + sred[5] + sred[8] + sred[11];
    }
}

// ---------------------------------------------------------------------------
// k4: outputs. word_feat[b,d] = (a*colsum_n + (ct-a)*n0 + (cb-a)*nL)/L, same
// for post. Sums the 8 colsum partials. grid = NB*ND/256 = 192.
// ---------------------------------------------------------------------------
__global__ __launch_bounds__(256) void k4_out(
    const float* __restrict__ news, const float* __restrict__ post,
    const float* __restrict__ csn_part, const float* __restrict__ csp_part,
    const float* __restrict__ abc, float* __restrict__ out)
{
    const int idx = blockIdx.x * 256 + threadIdx.x;
    if (idx >= NB * ND) return;
    const int b = idx / ND, d = idx - b * ND;
    const float a  = abc[b * 3 + 0];
    const float ct = abc[b * 3 + 1];
    const float cb = abc[b * 3 + 2];
    float cn = 0.f, cp = 0.f;
#pragma unroll
    for (int t = 0; t < 8; ++t) {
        cn += csn_part[((size_t)t * NB + b) * ND + d];
        cp += csp_part[((size_t)t * NB + b) * ND + d];
    }
    const size_t base = (size_t)b * NL * ND;
    const float n0 = news[base + d], nL = news[base + (size_t)(NL - 1) * ND + d];
    const float p0 = post[base + d], pL = post[base + (size_t)(NL - 1) * ND + d];
    const float invL = 1.f / NL;
    out[idx]           = (a * cn + (ct - a) * n0 + (cb - a) * nL) * invL;
    out[NB * ND + idx] = (a * cp + (ct - a) * p0 + (cb - a) * pL) * invL;
}

extern "C" void kernel_launch(void* const* d_in, const int* in_sizes, int n_in,
                              void* d_out, int out_size, void* d_ws, size_t ws_size,
                              hipStream_t stream) {
    const float* news     = (const float*)d_in[0];
    const float* post     = (const float*)d_in[1];
    const float* g        = (const float*)d_in[2];
    const float* bn_gamma = (const float*)d_in[3];
    const float* bn_beta  = (const float*)d_in[4];
    const float* lin_w    = (const float*)d_in[5];
    const float* lin_b    = (const float*)d_in[6];
    float* out = (float*)d_out;
    char*  ws  = (char*)d_ws;

    double* acc = (double*)(ws + OFF_ACC);
    float* csn  = (float*)(ws + OFF_CSN);
    float* csp  = (float*)(ws + OFF_CSP);
    float* cosv = (float*)(ws + OFF_COS);
    float* hi   = (float*)(ws + OFF_HI);
    float* ht   = (float*)(ws + OFF_HT);
    float* hb   = (float*)(ws + OFF_HB);
    float* abc  = (float*)(ws + OFF_ABC);

    hipMemsetAsync(acc, 0, 2 * sizeof(double), stream);

    k1_cos_colsum<<<NB * 8, 512, 0, stream>>>(news, post, cosv, csn, csp);
    k2_conv_stats<<<NB, 256, 0, stream>>>(cosv, g, hi, ht, hb, acc);
    k3_linear_softmax<<<NB, 256, 0, stream>>>(hi, ht, hb, lin_w, lin_b,
                                              bn_gamma, bn_beta, acc, abc);
    k4_out<<<192, 256, 0, stream>>>(news, post, csn, csp, abc, out);
}

// Round 4
// 91.746 us; speedup vs baseline: 1.8228x; 1.8228x over previous
//
#include <hip/hip_runtime.h>
#include <math.h>

#define NB 64
#define NL 512
#define ND 768

static constexpr float kCosEps = 1e-8f;
static constexpr double kBnEps = 1e-5;

// ---- workspace layout (bytes) ----
static constexpr size_t OFF_ACC = 0;                          // 2 doubles
static constexpr size_t OFF_CSN = 256;                        // [NB][ND] f32 colsum news (atomic)
static constexpr size_t SZ_CS   = (size_t)NB * ND * 4;        // 196608
static constexpr size_t OFF_CSP = OFF_CSN + SZ_CS;            // [NB][ND] f32 colsum post (atomic)
static constexpr size_t MEMSET_BYTES = OFF_CSP + SZ_CS;       // zero acc+csn+csp each call
static constexpr size_t OFF_COS = 393728;                     // [NB][NL] f32 cosine
static constexpr size_t SZ_BL   = (size_t)NB * NL * 4;
static constexpr size_t OFF_HI  = OFF_COS + SZ_BL;
static constexpr size_t OFF_HT  = OFF_HI + SZ_BL;
static constexpr size_t OFF_HB  = OFF_HT + SZ_BL;
static constexpr size_t OFF_ABC = OFF_HB + SZ_BL;

__device__ __forceinline__ float dot4(float4 a, float4 b) {
    return a.x * b.x + a.y * b.y + a.z * b.z + a.w * b.w;
}

// async global->LDS, 16 B per lane (wave-uniform LDS base, per-lane global src)
#define GLD16(ldst, gsrc)                                                        \
    __builtin_amdgcn_global_load_lds(                                            \
        (const __attribute__((address_space(1))) void*)(gsrc),                   \
        (__attribute__((address_space(3))) void*)(ldst), 16, 0, 0)

// ---------------------------------------------------------------------------
// k1 v4: m97-style global_load_lds double-buffered streaming.
// grid = NB*16 (batch x 32-row tile), block = 256 thr = 4 waves.
// Chunk = 4 news rows + 4 post rows = 24 KB; wave w stages & computes row w.
// Pipeline: stage(c+1) || compute(c) from LDS; one __syncthreads per chunk
// (drains vmcnt+lgkm). NO cross-lane ops in the loop; per-row partials
// (nn,pp,npd)[8] live in regs; one batched 24-chain shuffle reduce at end.
// Outstanding bytes are held in LDS, not VGPRs (r1-r3 showed VGPR-held load
// depth caps delivered BW at ~2.5 TB/s for this dual-stream pattern).
// ---------------------------------------------------------------------------
__global__ __launch_bounds__(256) void k1_cos_colsum(
    const float* __restrict__ news, const float* __restrict__ post,
    float* __restrict__ cosv, float* __restrict__ csn,
    float* __restrict__ csp)
{
    __shared__ float stage[2][8 * ND];   // 48 KB: rows 0-3 news, 4-7 post
    const int b    = blockIdx.x >> 4;
    const int t16  = blockIdx.x & 15;
    const int l0   = t16 * 32;
    const int tid  = threadIdx.x;
    const int wave = tid >> 6;           // 0..3
    const int lane = tid & 63;

    const float* nbase = news + ((size_t)b * NL + l0 + wave) * ND + lane * 4;
    const float* pbase = post + ((size_t)b * NL + l0 + wave) * ND + lane * 4;

    float nn[8], pp[8], npd[8];
    float an[12], ap[12];
#pragma unroll
    for (int k = 0; k < 12; ++k) { an[k] = 0.f; ap[k] = 0.f; }

    // ---- stage chunk 0 ----
#pragma unroll
    for (int k = 0; k < 3; ++k) {
        GLD16(&stage[0][wave * ND + k * 256],       nbase + k * 256);
        GLD16(&stage[0][(4 + wave) * ND + k * 256], pbase + k * 256);
    }
    __syncthreads();   // vmcnt(0) drain + barrier: chunk 0 resident

    for (int c = 0; c < 8; ++c) {
        const int cur = c & 1;
        if (c < 7) {
            const int nxt = cur ^ 1;
            const size_t goff = (size_t)(c + 1) * 4 * ND;   // +4 rows
#pragma unroll
            for (int k = 0; k < 3; ++k) {
                GLD16(&stage[nxt][wave * ND + k * 256],       nbase + goff + k * 256);
                GLD16(&stage[nxt][(4 + wave) * ND + k * 256], pbase + goff + k * 256);
            }
        }
        // compute row `wave` of chunk c from LDS
        const float4* ln = (const float4*)&stage[cur][wave * ND];
        const float4* lp = (const float4*)&stage[cur][(4 + wave) * ND];
        const float4 A0 = ln[lane], A1 = ln[lane + 64], A2 = ln[lane + 128];
        const float4 B0 = lp[lane], B1 = lp[lane + 64], B2 = lp[lane + 128];

        nn[c]  = dot4(A0, A0) + dot4(A1, A1) + dot4(A2, A2);
        pp[c]  = dot4(B0, B0) + dot4(B1, B1) + dot4(B2, B2);
        npd[c] = dot4(A0, B0) + dot4(A1, B1) + dot4(A2, B2);

        an[0] += A0.x; an[1] += A0.y; an[2]  += A0.z; an[3]  += A0.w;
        an[4] += A1.x; an[5] += A1.y; an[6]  += A1.z; an[7]  += A1.w;
        an[8] += A2.x; an[9] += A2.y; an[10] += A2.z; an[11] += A2.w;
        ap[0] += B0.x; ap[1] += B0.y; ap[2]  += B0.z; ap[3]  += B0.w;
        ap[4] += B1.x; ap[5] += B1.y; ap[6]  += B1.z; ap[7]  += B1.w;
        ap[8] += B2.x; ap[9] += B2.y; ap[10] += B2.z; ap[11] += B2.w;

        __syncthreads();   // next chunk landed; everyone done reading cur
    }

    // ---- batched cross-lane reduce: 24 independent chains, 6 stages ----
#pragma unroll
    for (int m = 1; m <= 32; m <<= 1) {
#pragma unroll
        for (int c = 0; c < 8; ++c) {
            nn[c]  += __shfl_xor(nn[c], m);
            pp[c]  += __shfl_xor(pp[c], m);
            npd[c] += __shfl_xor(npd[c], m);
        }
    }
    if (lane == 0) {
#pragma unroll
        for (int c = 0; c < 8; ++c) {
            const float dn = fmaxf(sqrtf(nn[c]), kCosEps) * fmaxf(sqrtf(pp[c]), kCosEps);
            cosv[b * NL + l0 + c * 4 + wave] = npd[c] / dn;
        }
    }

    // ---- colsum block-reduce (reuse stage[0]) + atomic accumulate ----
    {
        float4* wn = (float4*)&stage[0][wave * ND];
        float4* wp = (float4*)&stage[0][(4 + wave) * ND];
        wn[lane]       = make_float4(an[0], an[1], an[2], an[3]);
        wn[lane + 64]  = make_float4(an[4], an[5], an[6], an[7]);
        wn[lane + 128] = make_float4(an[8], an[9], an[10], an[11]);
        wp[lane]       = make_float4(ap[0], ap[1], ap[2], ap[3]);
        wp[lane + 64]  = make_float4(ap[4], ap[5], ap[6], ap[7]);
        wp[lane + 128] = make_float4(ap[8], ap[9], ap[10], ap[11]);
    }
    __syncthreads();
    for (int i = tid; i < ND; i += 256) {
        float sn = 0.f, sp = 0.f;
#pragma unroll
        for (int w = 0; w < 4; ++w) {
            sn += stage[0][w * ND + i];
            sp += stage[0][(4 + w) * ND + i];
        }
        atomicAdd(&csn[b * ND + i], sn);
        atomicAdd(&csp[b * ND + i], sp);
    }
}

// ---------------------------------------------------------------------------
// k2: 3-tap horizontal conv of cos row (3 vertical-weight variants) +
// fp64 global sum / sum-of-squares with multiplicities (1, L-2, 1).
// ---------------------------------------------------------------------------
__global__ __launch_bounds__(256) void k2_conv_stats(
    const float* __restrict__ cosv, const float* __restrict__ g,
    float* __restrict__ hi, float* __restrict__ ht, float* __restrict__ hb,
    double* __restrict__ acc)
{
    __shared__ float row[NL + 2];
    __shared__ double sred[8];
    const int b   = blockIdx.x;
    const int tid = threadIdx.x;
    if (tid == 0) { row[0] = 0.f; row[NL + 1] = 0.f; }
    for (int j = tid; j < NL; j += 256) row[j + 1] = cosv[b * NL + j];
    __syncthreads();

    const float ci0 = g[0] + g[3] + g[6], ci1 = g[1] + g[4] + g[7], ci2 = g[2] + g[5] + g[8];
    const float ct0 = g[3] + g[6],        ct1 = g[4] + g[7],        ct2 = g[5] + g[8];
    const float cb0 = g[0] + g[3],        cb1 = g[1] + g[4],        cb2 = g[2] + g[5];

    double s = 0.0, s2 = 0.0;
    for (int j = tid; j < NL; j += 256) {
        const float a = row[j], c = row[j + 1], d = row[j + 2];
        const float vi = ci0 * a + ci1 * c + ci2 * d;
        const float vt = ct0 * a + ct1 * c + ct2 * d;
        const float vb = cb0 * a + cb1 * c + cb2 * d;
        hi[b * NL + j] = vi; ht[b * NL + j] = vt; hb[b * NL + j] = vb;
        s  += (double)vi * (NL - 2) + (double)vt + (double)vb;
        s2 += (double)vi * vi * (NL - 2) + (double)vt * vt + (double)vb * vb;
    }
    const int lane = tid & 63, wave = tid >> 6;
#pragma unroll
    for (int m = 32; m >= 1; m >>= 1) { s += __shfl_xor(s, m); s2 += __shfl_xor(s2, m); }
    if (lane == 0) { sred[wave] = s; sred[4 + wave] = s2; }
    __syncthreads();
    if (tid == 0) {
        atomicAdd(&acc[0], sred[0] + sred[1] + sred[2] + sred[3]);
        atomicAdd(&acc[1], sred[4] + sred[5] + sred[6] + sred[7]);
    }
}

// ---------------------------------------------------------------------------
// k3: normalize (global BN), z = h_hat @ W^T + b for the 3 variants,
// collapsed softmax over l (multiplicities 1, L-2, 1), sum over n.
// ---------------------------------------------------------------------------
__global__ __launch_bounds__(256) void k3_linear_softmax(
    const float* __restrict__ hi, const float* __restrict__ ht,
    const float* __restrict__ hb, const float* __restrict__ W,
    const float* __restrict__ bias, const float* __restrict__ gamma,
    const float* __restrict__ beta, const double* __restrict__ acc,
    float* __restrict__ abc)
{
    __shared__ float shi[NL], sht[NL], shb[NL];
    __shared__ float sred[12];
    const int b   = blockIdx.x;
    const int tid = threadIdx.x;

    const double N   = (double)NB * NL * NL;
    const double mu  = acc[0] / N;
    const double var = acc[1] / N - mu * mu;
    const float  sc  = gamma[0] * (float)(1.0 / sqrt(var + kBnEps));
    const float  sh  = beta[0] - (float)mu * sc;

    for (int j = tid; j < NL; j += 256) {
        shi[j] = hi[b * NL + j] * sc + sh;
        sht[j] = ht[b * NL + j] * sc + sh;
        shb[j] = hb[b * NL + j] * sc + sh;
    }
    __syncthreads();

    const float4* s4i = (const float4*)shi;
    const float4* s4t = (const float4*)sht;
    const float4* s4b = (const float4*)shb;

    float sa = 0.f, st = 0.f, sb = 0.f;
    for (int n = tid; n < NL; n += 256) {
        const float4* wr = (const float4*)(W + (size_t)n * NL);
        float zi = 0.f, zt = 0.f, zb = 0.f;
        for (int m = 0; m < NL / 4; ++m) {
            const float4 w  = wr[m];
            const float4 vi = s4i[m], vt = s4t[m], vb = s4b[m];
            zi += w.x * vi.x + w.y * vi.y + w.z * vi.z + w.w * vi.w;
            zt += w.x * vt.x + w.y * vt.y + w.z * vt.z + w.w * vt.w;
            zb += w.x * vb.x + w.y * vb.y + w.z * vb.z + w.w * vb.w;
        }
        const float bv = bias[n];
        zi += bv; zt += bv; zb += bv;
        const float M  = fmaxf(zi, fmaxf(zt, zb));
        const float ei = expf(zi - M), et = expf(zt - M), eb = expf(zb - M);
        const float r  = 1.f / ((float)(NL - 2) * ei + et + eb);
        sa += ei * r; st += et * r; sb += eb * r;
    }
    const int lane = tid & 63, wave = tid >> 6;
#pragma unroll
    for (int m = 32; m >= 1; m >>= 1) {
        sa += __shfl_xor(sa, m); st += __shfl_xor(st, m); sb += __shfl_xor(sb, m);
    }
    if (lane == 0) { sred[wave * 3] = sa; sred[wave * 3 + 1] = st; sred[wave * 3 + 2] = sb; }
    __syncthreads();
    if (tid == 0) {
        abc[b * 3 + 0] = sred[0] + sred[3] + sred[6] + sred[9];
        abc[b * 3 + 1] = sred[1] + sred[4] + sred[7] + sred[10];
        abc[b * 3 + 2] = sred[2] + sred[5] + sred[8] + sred[11];
    }
}

// ---------------------------------------------------------------------------
// k4: outputs. word_feat[b,d] = (a*colsum_n + (ct-a)*n0 + (cb-a)*nL)/L, same
// for post. grid = NB*ND/256 = 192.
// ---------------------------------------------------------------------------
__global__ __launch_bounds__(256) void k4_out(
    const float* __restrict__ news, const float* __restrict__ post,
    const float* __restrict__ csn, const float* __restrict__ csp,
    const float* __restrict__ abc, float* __restrict__ out)
{
    const int idx = blockIdx.x * 256 + threadIdx.x;
    if (idx >= NB * ND) return;
    const int b = idx / ND, d = idx - b * ND;
    const float a  = abc[b * 3 + 0];
    const float ct = abc[b * 3 + 1];
    const float cb = abc[b * 3 + 2];
    const float cn = csn[idx];
    const float cp = csp[idx];
    const size_t base = (size_t)b * NL * ND;
    const float n0 = news[base + d], nL = news[base + (size_t)(NL - 1) * ND + d];
    const float p0 = post[base + d], pL = post[base + (size_t)(NL - 1) * ND + d];
    const float invL = 1.f / NL;
    out[idx]           = (a * cn + (ct - a) * n0 + (cb - a) * nL) * invL;
    out[NB * ND + idx] = (a * cp + (ct - a) * p0 + (cb - a) * pL) * invL;
}

extern "C" void kernel_launch(void* const* d_in, const int* in_sizes, int n_in,
                              void* d_out, int out_size, void* d_ws, size_t ws_size,
                              hipStream_t stream) {
    const float* news     = (const float*)d_in[0];
    const float* post     = (const float*)d_in[1];
    const float* g        = (const float*)d_in[2];
    const float* bn_gamma = (const float*)d_in[3];
    const float* bn_beta  = (const float*)d_in[4];
    const float* lin_w    = (const float*)d_in[5];
    const float* lin_b    = (const float*)d_in[6];
    float* out = (float*)d_out;
    char*  ws  = (char*)d_ws;

    double* acc = (double*)(ws + OFF_ACC);
    float* csn  = (float*)(ws + OFF_CSN);
    float* csp  = (float*)(ws + OFF_CSP);
    float* cosv = (float*)(ws + OFF_COS);
    float* hi   = (float*)(ws + OFF_HI);
    float* ht   = (float*)(ws + OFF_HT);
    float* hb   = (float*)(ws + OFF_HB);
    float* abc  = (float*)(ws + OFF_ABC);

    // zero acc + csn + csp (atomic accumulation targets) every call
    hipMemsetAsync(ws, 0, MEMSET_BYTES, stream);

    k1_cos_colsum<<<NB * 16, 256, 0, stream>>>(news, post, cosv, csn, csp);
    k2_conv_stats<<<NB, 256, 0, stream>>>(cosv, g, hi, ht, hb, acc);
    k3_linear_softmax<<<NB, 256, 0, stream>>>(hi, ht, hb, lin_w, lin_b,
                                              bn_gamma, bn_beta, acc, abc);
    k4_out<<<192, 256, 0, stream>>>(news, post, csn, csp, abc, out);
}